// Round 2
// 451.807 us; speedup vs baseline: 1.0677x; 1.0677x over previous
//
#include <hip/hip_runtime.h>

#define NN 50000
#define NE 800000

typedef __attribute__((ext_vector_type(8))) short bf16x8;
typedef __attribute__((ext_vector_type(4))) float f32x4;
typedef __attribute__((ext_vector_type(2))) float f32x2;

__device__ __forceinline__ unsigned short f2bf(float f) {
    union { float f; unsigned u; } v; v.f = f;
    unsigned r = v.u + 0x7FFFu + ((v.u >> 16) & 1u);
    return (unsigned short)(r >> 16);
}

// 32-bit-offset gathers (uniform 64-bit base + 32-bit voffset)
__device__ __forceinline__ int4 ld_ep(const int4* ep, unsigned idx) {
    return *(const int4*)((const char*)ep + (size_t)(idx * 16u));
}
__device__ __forceinline__ unsigned ld_xu(const unsigned* X, unsigned byteoff) {
    return *(const unsigned*)((const char*)X + (size_t)byteoff);
}

// dword of 2 packed bf16 (lo = even channel, hi = odd channel) -> f32x2
__device__ __forceinline__ f32x2 unpack2(unsigned u) {
    union { unsigned u; float f; } a, b;
    a.u = u << 16;
    b.u = u & 0xFFFF0000u;
    return f32x2{a.f, b.f};
}

// bf16 LDS A-fragment layout (16 nodes/block):
//   element (kstep kk, r = k&31, node m) at ushort index
//   kk*544 + (r>>3)*136 + m*8 + (r&7)
__device__ __forceinline__ int us_idx(int kk, int r, int m) {
    return kk*544 + (r >> 3)*136 + m*8 + (r & 7);
}

// packed hat-weight accumulate on channel pairs:
// h[25] (f32x2) += x(2ch) * wx(r0) * wy(r1); optional hs += x.
// Per-lane p differs by edge slot, so one call serves 2 edges x 2 channels.
template<bool HS>
__device__ __forceinline__ void edge_acc2(f32x2* h, f32x2& hs, const int4& p, f32x2 x) {
    const f32x2 zero = {0.f, 0.f};
    f32x2 vp = {__int_as_float(p.z), __int_as_float(p.w)};
    f32x2 wxy[5];
#pragma unroll
    for (int r = 0; r < 5; ++r) {
        f32x2 wr = 1.f - __builtin_elementwise_abs(vp - (float)r);
        wxy[r] = __builtin_elementwise_max(wr, zero);
    }
    if (HS) hs += x;
#pragma unroll
    for (int r1 = 0; r1 < 5; ++r1) {
        f32x2 ty = x * wxy[r1].y;
#pragma unroll
        for (int r0 = 0; r0 < 5; ++r0)
            h[r1*5 + r0] += wxy[r0].x * ty;   // expect v_pk_fma_f32
    }
}

// reduce partials across the edge-slot partner lane.
// Each lane owns channel (2*chp + eh); its own partial is (eh ? y : x),
// the partner lane's partial FOR MY channel is the partner's opposite
// component, fetched with shfl_xor over the edge-slot stride.
__device__ __forceinline__ float eh_reduce(f32x2 v, int eh, int stride) {
    float mine  = eh ? v.y : v.x;
    float other = eh ? v.x : v.y;
    return mine + __shfl_xor(other, stride);
}

// ---------------- setup kernels ----------------
__global__ __launch_bounds__(256) void k_zero(int* degi, int* cur, float* stats) {
    int i = blockIdx.x*256 + threadIdx.x;
    int stride = gridDim.x*256;
    for (int j = i; j < NN; j += stride) { degi[j] = 0; cur[j] = 0; }
    if (i < 384) stats[i] = 0.f;
}

__global__ __launch_bounds__(256) void k_hist(const int* __restrict__ dst, int* degi) {
    int e = blockIdx.x*256 + threadIdx.x;
    if (e < NE) atomicAdd(&degi[dst[e]], 1);
}

__global__ __launch_bounds__(256) void k_scan_block(const int* __restrict__ degi,
                                                    int* off, int* bsum) {
    __shared__ int sh[256];
    int t = threadIdx.x;
    int base = blockIdx.x * 1024;
    int v[4]; int s = 0;
#pragma unroll
    for (int j = 0; j < 4; j++) {
        int idx = base + t*4 + j;
        v[j] = (idx < NN) ? degi[idx] : 0;
        s += v[j];
    }
    sh[t] = s; __syncthreads();
    for (int ofs = 1; ofs < 256; ofs <<= 1) {
        int x = (t >= ofs) ? sh[t - ofs] : 0;
        __syncthreads();
        sh[t] += x;
        __syncthreads();
    }
    int ex = sh[t] - s;
#pragma unroll
    for (int j = 0; j < 4; j++) {
        int idx = base + t*4 + j;
        if (idx < NN) off[idx] = ex;
        ex += v[j];
    }
    if (t == 255) bsum[blockIdx.x] = sh[255];
}

__global__ __launch_bounds__(256) void k_scan_top(const int* __restrict__ bsum,
                                                  int* bpre, int nb) {
    __shared__ int sh[256];
    int t = threadIdx.x;
    int s = (t < nb) ? bsum[t] : 0;
    sh[t] = s; __syncthreads();
    for (int ofs = 1; ofs < 256; ofs <<= 1) {
        int x = (t >= ofs) ? sh[t - ofs] : 0;
        __syncthreads();
        sh[t] += x;
        __syncthreads();
    }
    if (t < nb) bpre[t] = sh[t] - s;
}

__global__ __launch_bounds__(256) void k_scan_add(int* off, const int* __restrict__ bpre) {
    int i = blockIdx.x*256 + threadIdx.x;
    if (i < NN) off[i] += bpre[i >> 10];
    if (i == 0) off[NN] = NE;
}

// ep = (src, 0, v0, v1) with v = pseudo*4 in [0,4); hat weights derive from v.
__global__ __launch_bounds__(256) void k_scatter(const int* __restrict__ src,
                                                 const int* __restrict__ dst,
                                                 const float* __restrict__ ea,
                                                 const int* __restrict__ off, int* cur,
                                                 int4* __restrict__ ep) {
    int e = blockIdx.x*256 + threadIdx.x;
    if (e >= NE) return;
    int d = dst[e];
    int p = off[d] + atomicAdd(&cur[d], 1);
    float v0 = ea[2*e]     * 4.f;
    float v1 = ea[2*e + 1] * 4.f;
    ep[p] = make_int4(src[e], 0, __float_as_int(v0), __float_as_int(v1));
}

// x (f32, [NN][32]) -> packed bf16 dwords
__global__ __launch_bounds__(256) void k_xbf(const float* __restrict__ x,
                                             unsigned short* __restrict__ xb) {
    int i = blockIdx.x*256 + threadIdx.x;
    if (i >= NN*8) return;
    float4 v = ((const float4*)x)[i];
    uint2 pk;
    pk.x = (unsigned)f2bf(v.x) | ((unsigned)f2bf(v.y) << 16);
    pk.y = (unsigned)f2bf(v.z) | ((unsigned)f2bf(v.w) << 16);
    ((uint2*)xb)[i] = pk;
}

// Pre-tile [W ; root] (f32, row-major [K,64]) into MFMA-B bf16 layout:
// Wb[((kk*4+cot)*64+lane)*8 + j] = src[k = kk*32+(lane>>4)*8+j][co = 16*cot+(lane&15)]
__global__ __launch_bounds__(256) void k_wprep(const float* __restrict__ W,
                                               const float* __restrict__ root,
                                               int KTC, unsigned short* Wb) {
    int tid = blockIdx.x*256 + threadIdx.x;
    int lane = tid & 63, cot = (tid >> 6) & 3, kk = tid >> 8;
    int co = 16*cot + (lane & 15);
    int kbase = kk*32 + ((lane >> 4) * 8);
    union { unsigned short s[8]; uint4 v; } u;
#pragma unroll
    for (int j = 0; j < 8; j++) {
        int k = kbase + j;
        float val = (k < KTC) ? W[(size_t)k*64 + co] : root[(size_t)(k - KTC)*64 + co];
        u.s[j] = f2bf(val);
    }
    *(uint4*)(Wb + (size_t)tid * 8) = u.v;
}

// ---------------- conv1 + convS fused: 16 nodes/block ----------------
// 512 threads, 8 waves. Half-wave (t>>5) owns node g.
// Within half-wave: chp = q&15 (bf16 channel pair), eh = q>>4 (edge slot).
// 4 edges per iteration per node, packed f32x2 channel math.
__global__ __launch_bounds__(512, 4) void k_conv1s(
        const unsigned* __restrict__ Xbf,        // [NN][16] dwords (32 bf16 ch)
        const int* __restrict__ off,
        const int4* __restrict__ ep,
        const unsigned short* __restrict__ Wb1,
        const unsigned short* __restrict__ WbS,
        const float* __restrict__ b1,
        const float* __restrict__ bs,
        float* __restrict__ agg1,
        float* __restrict__ aggS) {
    __shared__ __align__(16) unsigned short hb[28*544];  // 30.5 KB
    const int t = threadIdx.x;
    const int g = t >> 5;          // node slot 0..15
    const int q = t & 31;
    const int chp = q & 15;        // channel pair -> channels 2chp, 2chp+1
    const int eh = q >> 4;         // edge slot
    const int n0 = blockIdx.x * 16;
    const int n = n0 + g;

    f32x2 h[25], hs = {0.f, 0.f};
#pragma unroll
    for (int i = 0; i < 25; ++i) h[i] = f32x2{0.f, 0.f};

    const int ebeg = off[n], eend = off[n + 1];
    const int last = eend - 1;
    const float rdeg = 1.f / (float)max(eend - ebeg, 1);

    for (int i = ebeg; i < eend; i += 4) {
        const int e0 = i + eh, e1 = i + 2 + eh;
        int4 p0 = ld_ep(ep, (unsigned)min(e0, last));
        int4 p1 = ld_ep(ep, (unsigned)min(e1, last));
        unsigned u0 = ld_xu(Xbf, (unsigned)p0.x * 64u + (unsigned)chp * 4u);
        unsigned u1 = ld_xu(Xbf, (unsigned)p1.x * 64u + (unsigned)chp * 4u);
        if (e0 > last) u0 = 0u;
        if (e1 > last) u1 = 0u;
        edge_acc2<true>(h, hs, p0, unpack2(u0));
        edge_acc2<true>(h, hs, p1, unpack2(u1));
    }

    // ---- eh-reduce (shfl_xor over the 16-lane edge-slot stride) and dump ----
    // Lane (chp,eh) owns channel c = 2*chp + eh.
    const int c = 2*chp + eh;
    const int bw = us_idx(0, c, g);
#pragma unroll
    for (int wi = 0; wi < 25; ++wi)
        hb[wi*544 + bw] = f2bf(eh_reduce(h[wi], eh, 16) * rdeg);
    hb[26*544 + bw] = f2bf(eh_reduce(hs, eh, 16) * rdeg);
    {
        unsigned ux = Xbf[(unsigned)n * 16u + (unsigned)chp];
        unsigned short xb = eh ? (unsigned short)(ux >> 16)
                               : (unsigned short)(ux & 0xFFFFu);
        hb[25*544 + bw] = xb;   // x for root (r1)
        hb[27*544 + bw] = xb;   // x for root (rs)
    }
    __syncthreads();

    // ---- phase B (unchanged) ----
    const int lane = t & 63, w = t >> 6;
    const int m = lane & 15, qq = lane >> 4;
    const int co = (w & 3)*16 + m;
    if (w < 4) {
        f32x4 acc = {0.f, 0.f, 0.f, 0.f};
        for (int kk = 0; kk < 26; ++kk) {
            bf16x8 av = *(const bf16x8*)&hb[kk*544 + qq*136 + m*8];
            bf16x8 bv = *(const bf16x8*)(Wb1 + (size_t)((kk*4 + w)*64 + lane) * 8);
            acc = __builtin_amdgcn_mfma_f32_16x16x32_bf16(av, bv, acc, 0, 0, 0);
        }
        const float bb = b1[co];
#pragma unroll
        for (int r = 0; r < 4; ++r)
            agg1[(size_t)(n0 + qq*4 + r)*64 + co] = acc[r] + bb;
    } else {
        f32x4 accs = {0.f, 0.f, 0.f, 0.f};
#pragma unroll
        for (int s = 0; s < 2; ++s) {
            bf16x8 av = *(const bf16x8*)&hb[(26 + s)*544 + qq*136 + m*8];
            bf16x8 bv = *(const bf16x8*)(WbS + (size_t)((s*4 + (w & 3))*64 + lane) * 8);
            accs = __builtin_amdgcn_mfma_f32_16x16x32_bf16(av, bv, accs, 0, 0, 0);
        }
        const float bb = bs[co];
#pragma unroll
        for (int r = 0; r < 4; ++r)
            aggS[(size_t)(n0 + qq*4 + r)*64 + co] = accs[r] + bb;
    }
}

// ---------------- conv2: 16 nodes/block ----------------
// 512 threads, 8 waves. Wave w owns nodes 2w, 2w+1 sequentially.
// Lanes: chp = lane&31 (bf16 channel pair of 64 ch), eh = lane>>5 (edge slot):
// 2 edges per wave instruction, packed f32x2 channel math.
__global__ __launch_bounds__(512, 4) void k_conv2(
        const unsigned* __restrict__ Xbf,        // h1 bf16: [NN][32] dwords (64 ch)
        const int* __restrict__ off,
        const int4* __restrict__ ep,
        const unsigned short* __restrict__ Wb2,
        const float* __restrict__ b2,
        float* __restrict__ agg) {
    __shared__ __align__(16) unsigned short hb[52*544];  // 56.6 KB
    const int t = threadIdx.x, lane = t & 63, w = t >> 6;
    const int n0 = blockIdx.x * 16;
    const int chp = lane & 31, eh = lane >> 5;
    const int c = 2*chp + eh;          // channel owned after eh-reduce
    const int kh = c >> 5, r = c & 31; // k = wi*64 + c -> kstep wi*2+kh

#pragma unroll
    for (int nn = 0; nn < 2; ++nn) {
        const int g = 2*w + nn;
        const int n = n0 + g;
        f32x2 h[25]; f32x2 hsd = {0.f, 0.f};
#pragma unroll
        for (int i = 0; i < 25; ++i) h[i] = f32x2{0.f, 0.f};

        const int ebeg = off[n], eend = off[n + 1];
        const int last = eend - 1;
        const float rdeg = 1.f / (float)max(eend - ebeg, 1);

        for (int i = ebeg; i < eend; i += 4) {
            const int e0 = i + eh, e1 = i + 2 + eh;
            int4 p0 = ld_ep(ep, (unsigned)min(e0, last));
            int4 p1 = ld_ep(ep, (unsigned)min(e1, last));
            unsigned u0 = ld_xu(Xbf, (unsigned)p0.x * 128u + (unsigned)chp * 4u);
            unsigned u1 = ld_xu(Xbf, (unsigned)p1.x * 128u + (unsigned)chp * 4u);
            if (e0 > last) u0 = 0u;
            if (e1 > last) u1 = 0u;
            edge_acc2<false>(h, hsd, p0, unpack2(u0));
            edge_acc2<false>(h, hsd, p1, unpack2(u1));
        }

        // eh-reduce via shfl_xor(32); dump bf16 fragments
        const int bw = us_idx(0, r, g);
#pragma unroll
        for (int wi = 0; wi < 25; ++wi)
            hb[(wi*2 + kh)*544 + bw] = f2bf(eh_reduce(h[wi], eh, 32) * rdeg);
        {
            unsigned ux = Xbf[(unsigned)n * 32u + (unsigned)chp];
            hb[(50 + kh)*544 + bw] =
                (unsigned short)(eh ? (ux >> 16) : (ux & 0xFFFFu));
        }
    }
    __syncthreads();

    if (w >= 4) return;

    const int m = lane & 15, qq = lane >> 4;
    f32x4 acc = {0.f, 0.f, 0.f, 0.f};
    for (int kk = 0; kk < 52; ++kk) {
        bf16x8 av = *(const bf16x8*)&hb[kk*544 + qq*136 + m*8];
        bf16x8 bv = *(const bf16x8*)(Wb2 + (size_t)((kk*4 + w)*64 + lane) * 8);
        acc = __builtin_amdgcn_mfma_f32_16x16x32_bf16(av, bv, acc, 0, 0, 0);
    }
    const int co = w*16 + m;
    const float bb = b2[co];
#pragma unroll
    for (int rr = 0; rr < 4; ++rr)
        agg[(size_t)(n0 + qq*4 + rr)*64 + co] = acc[rr] + bb;
}

// ---------------- batch norm ----------------
__global__ __launch_bounds__(256) void k_bnstats(const float* __restrict__ agg, float* stats) {
    __shared__ float sh0[256], sh1[256];
    int t = threadIdx.x;
    float s = 0.f, ss = 0.f;
    int stride = gridDim.x * 256;
    for (int i = blockIdx.x*256 + t; i < NN*64; i += stride) {
        float v = agg[i];
        s += v; ss += v*v;
    }
    sh0[t] = s; sh1[t] = ss;
    __syncthreads();
    if (t < 64) {
        float a = sh0[t] + sh0[t+64] + sh0[t+128] + sh0[t+192];
        float b = sh1[t] + sh1[t+64] + sh1[t+128] + sh1[t+192];
        atomicAdd(&stats[t], a);
        atomicAdd(&stats[64 + t], b);
    }
}

__device__ __forceinline__ float eluf(float u) { return u > 0.f ? u : expm1f(u); }

// BN + ELU, emitting packed bf16 h1 (feeds conv2's gathers directly)
__global__ __launch_bounds__(256) void k_bn_elu(const float* __restrict__ agg,
                                                const float* __restrict__ stats,
                                                const float* __restrict__ gamma,
                                                const float* __restrict__ beta,
                                                unsigned short* __restrict__ outb) {
    int i = blockIdx.x*256 + threadIdx.x;
    if (i >= NN*16) return;
    float4 v = ((const float4*)agg)[i];
    float r[4] = {v.x, v.y, v.z, v.w};
    int c0 = (i << 2) & 63;
#pragma unroll
    for (int j = 0; j < 4; j++) {
        int c = c0 + j;
        float mu = stats[c] * (1.f/NN);
        float var = stats[64 + c] * (1.f/NN) - mu*mu;
        float sc = gamma[c] * rsqrtf(fmaxf(var, 0.f) + 1e-5f);
        r[j] = eluf((r[j] - mu)*sc + beta[c]);
    }
    uint2 pk;
    pk.x = (unsigned)f2bf(r[0]) | ((unsigned)f2bf(r[1]) << 16);
    pk.y = (unsigned)f2bf(r[2]) | ((unsigned)f2bf(r[3]) << 16);
    ((uint2*)outb)[i] = pk;
}

__global__ __launch_bounds__(256) void k_bn_final(const float* __restrict__ a2,
                                                  const float* __restrict__ st2,
                                                  const float* __restrict__ g2,
                                                  const float* __restrict__ be2,
                                                  const float* __restrict__ as,
                                                  const float* __restrict__ sts,
                                                  const float* __restrict__ gs,
                                                  const float* __restrict__ bes,
                                                  float* __restrict__ out) {
    int i = blockIdx.x*256 + threadIdx.x;
    if (i >= NN*16) return;
    float4 v2 = ((const float4*)a2)[i];
    float4 vs = ((const float4*)as)[i];
    float r2v[4] = {v2.x, v2.y, v2.z, v2.w};
    float rsv[4] = {vs.x, vs.y, vs.z, vs.w};
    float o[4];
    int c0 = (i << 2) & 63;
#pragma unroll
    for (int j = 0; j < 4; j++) {
        int c = c0 + j;
        float mu2 = st2[c] * (1.f/NN);
        float var2 = st2[64 + c] * (1.f/NN) - mu2*mu2;
        float sc2 = g2[c] * rsqrtf(fmaxf(var2, 0.f) + 1e-5f);
        float mus = sts[c] * (1.f/NN);
        float vars = sts[64 + c] * (1.f/NN) - mus*mus;
        float scs = gs[c] * rsqrtf(fmaxf(vars, 0.f) + 1e-5f);
        float u = (r2v[j] - mu2)*sc2 + be2[c] + (rsv[j] - mus)*scs + bes[c];
        o[j] = eluf(u);
    }
    ((float4*)out)[i] = make_float4(o[0], o[1], o[2], o[3]);
}

extern "C" void kernel_launch(void* const* d_in, const int* in_sizes, int n_in,
                              void* d_out, int out_size, void* d_ws, size_t ws_size,
                              hipStream_t stream) {
    const float* x   = (const float*)d_in[0];
    const int*   ei  = (const int*)d_in[1];
    const float* ea  = (const float*)d_in[2];
    const float* w1  = (const float*)d_in[3];
    const float* r1  = (const float*)d_in[4];
    const float* b1  = (const float*)d_in[5];
    const float* g1  = (const float*)d_in[6];
    const float* be1 = (const float*)d_in[7];
    const float* w2  = (const float*)d_in[8];
    const float* r2  = (const float*)d_in[9];
    const float* b2  = (const float*)d_in[10];
    const float* g2  = (const float*)d_in[11];
    const float* be2 = (const float*)d_in[12];
    const float* wsN = (const float*)d_in[13];
    const float* rs  = (const float*)d_in[14];
    const float* bs  = (const float*)d_in[15];
    const float* gs  = (const float*)d_in[16];
    const float* bes = (const float*)d_in[17];
    const int* srcp = ei;
    const int* dstp = ei + NE;

    char* wsb = (char*)d_ws;
    size_t o = 0;
    auto alloc = [&](size_t bytes) -> char* {
        char* p = wsb + o;
        o += (bytes + 255) & ~(size_t)255;
        return p;
    };
    int*    degi    = (int*)   alloc((size_t)NN * 4);
    int*    cur     = (int*)   alloc((size_t)NN * 4);
    int*    off     = (int*)   alloc((size_t)(NN + 1) * 4);
    int*    bsum    = (int*)   alloc(256 * 4);
    int*    bpre    = (int*)   alloc(256 * 4);
    int4*   ep      = (int4*)  alloc((size_t)NE * 16);
    unsigned short* Wb1 = (unsigned short*)alloc(26 * 4096);
    unsigned short* WbS = (unsigned short*)alloc(2 * 4096);
    unsigned short* Wb2 = (unsigned short*)alloc(52 * 4096);
    float*  agg1    = (float*) alloc((size_t)NN * 64 * 4);  // reused for conv2 output
    float*  aggS    = (float*) alloc((size_t)NN * 64 * 4);
    unsigned short* h1bf = (unsigned short*)alloc((size_t)NN * 64 * 2);
    unsigned short* xbf  = (unsigned short*)alloc((size_t)NN * 32 * 2);
    float*  stats   = (float*) alloc(384 * 4);
    (void)ws_size; (void)in_sizes; (void)n_in; (void)out_size;

    float* out = (float*)d_out;

    k_zero<<<196, 256, 0, stream>>>(degi, cur, stats);
    k_hist<<<3125, 256, 0, stream>>>(dstp, degi);
    k_scan_block<<<49, 256, 0, stream>>>(degi, off, bsum);
    k_scan_top<<<1, 256, 0, stream>>>(bsum, bpre, 49);
    k_scan_add<<<196, 256, 0, stream>>>(off, bpre);
    k_scatter<<<3125, 256, 0, stream>>>(srcp, dstp, ea, off, cur, ep);

    k_xbf<<<1563, 256, 0, stream>>>(x, xbf);
    k_wprep<<<26, 256, 0, stream>>>(w1, r1, 800, Wb1);
    k_wprep<<<2, 256, 0, stream>>>(wsN, rs, 32, WbS);
    k_wprep<<<52, 256, 0, stream>>>(w2, r2, 1600, Wb2);

    k_conv1s<<<3125, 512, 0, stream>>>((const unsigned*)xbf, off, ep, Wb1, WbS,
                                       b1, bs, agg1, aggS);
    k_bnstats<<<256, 256, 0, stream>>>(agg1, stats);
    k_bn_elu<<<3125, 256, 0, stream>>>(agg1, stats, g1, be1, h1bf);

    k_conv2<<<3125, 512, 0, stream>>>((const unsigned*)h1bf, off, ep, Wb2, b2, agg1);
    k_bnstats<<<256, 256, 0, stream>>>(agg1, stats + 128);
    k_bnstats<<<256, 256, 0, stream>>>(aggS, stats + 256);
    k_bn_final<<<3125, 256, 0, stream>>>(agg1, stats + 128, g2, be2,
                                         aggS, stats + 256, gs, bes, out);
}

// Round 3
// 446.658 us; speedup vs baseline: 1.0800x; 1.0115x over previous
//
#include <hip/hip_runtime.h>

#define NN 50000
#define NE 800000

typedef __attribute__((ext_vector_type(8))) short bf16x8;
typedef __attribute__((ext_vector_type(4))) float f32x4;
typedef __attribute__((ext_vector_type(2))) float f32x2;

__device__ __forceinline__ unsigned short f2bf(float f) {
    union { float f; unsigned u; } v; v.f = f;
    unsigned r = v.u + 0x7FFFu + ((v.u >> 16) & 1u);
    return (unsigned short)(r >> 16);
}

// 32-bit-offset gathers (uniform 64-bit base + 32-bit voffset)
__device__ __forceinline__ int4 ld_ep(const int4* ep, unsigned idx) {
    return *(const int4*)((const char*)ep + (size_t)(idx * 16u));
}
__device__ __forceinline__ unsigned ld_xu(const unsigned* X, unsigned byteoff) {
    return *(const unsigned*)((const char*)X + (size_t)byteoff);
}

// dword of 2 packed bf16 (lo = even channel, hi = odd channel) -> f32x2
__device__ __forceinline__ f32x2 unpack2(unsigned u) {
    union { unsigned u; float f; } a, b;
    a.u = u << 16;
    b.u = u & 0xFFFF0000u;
    return f32x2{a.f, b.f};
}

// ---- forced VOP3P packed-f32 with op_sel broadcasts ----
// ty = {w.hi * x.lo, w.hi * x.hi}   (broadcast w.hi to both halves)
__device__ __forceinline__ f32x2 pk_mul_hib(f32x2 w, f32x2 x) {
    f32x2 d;
    asm("v_pk_mul_f32 %0, %1, %2 op_sel:[1,0] op_sel_hi:[1,1]"
        : "=v"(d) : "v"(w), "v"(x));
    return d;
}
// h += {w.lo * t.lo, w.lo * t.hi}   (broadcast w.lo to both halves)
__device__ __forceinline__ void pk_fma_lob(f32x2& h, f32x2 w, f32x2 t) {
    asm("v_pk_fma_f32 %0, %1, %2, %0 op_sel:[0,0,0] op_sel_hi:[0,1,1]"
        : "+v"(h) : "v"(w), "v"(t));
}

// bf16 LDS A-fragment layout (16 nodes/block):
//   element (kstep kk, r = k&31, node m) at ushort index
//   kk*544 + (r>>3)*136 + m*8 + (r&7)
__device__ __forceinline__ int us_idx(int kk, int r, int m) {
    return kk*544 + (r >> 3)*136 + m*8 + (r & 7);
}

// packed hat-weight accumulate on channel pairs:
// h[25] (f32x2) += x(2ch) * wx(r0) * wy(r1); optional hs += x.
// Per-lane p differs by edge slot, so one call serves 2 edges x 2 channels.
// Inner 30 ops are forced v_pk_* (compiler scalarizes generic vector code).
template<bool HS>
__device__ __forceinline__ void edge_acc2(f32x2* h, f32x2& hs, const int4& p, f32x2 x) {
    const f32x2 zero = {0.f, 0.f};
    f32x2 vp = {__int_as_float(p.z), __int_as_float(p.w)};
    f32x2 wxy[5];
#pragma unroll
    for (int r = 0; r < 5; ++r) {
        f32x2 wr = 1.f - __builtin_elementwise_abs(vp - (float)r);
        wxy[r] = __builtin_elementwise_max(wr, zero);
    }
    if (HS) hs += x;
#pragma unroll
    for (int r1 = 0; r1 < 5; ++r1) {
        f32x2 ty = pk_mul_hib(wxy[r1], x);   // x * wy[r1]
#pragma unroll
        for (int r0 = 0; r0 < 5; ++r0)
            pk_fma_lob(h[r1*5 + r0], wxy[r0], ty);  // += wx[r0] * ty
    }
}

// reduce partials across the edge-slot partner lane.
// Each lane owns channel (2*chp + eh); its own partial is (eh ? y : x),
// the partner lane's partial FOR MY channel is the partner's opposite
// component, fetched with shfl_xor over the edge-slot stride.
__device__ __forceinline__ float eh_reduce(f32x2 v, int eh, int stride) {
    float mine  = eh ? v.y : v.x;
    float other = eh ? v.x : v.y;
    return mine + __shfl_xor(other, stride);
}

// ---------------- setup kernels ----------------
__global__ __launch_bounds__(256) void k_zero(int* degi, int* cur, float* stats) {
    int i = blockIdx.x*256 + threadIdx.x;
    int stride = gridDim.x*256;
    for (int j = i; j < NN; j += stride) { degi[j] = 0; cur[j] = 0; }
    if (i < 384) stats[i] = 0.f;
}

__global__ __launch_bounds__(256) void k_hist(const int* __restrict__ dst, int* degi) {
    int e = blockIdx.x*256 + threadIdx.x;
    if (e < NE) atomicAdd(&degi[dst[e]], 1);
}

__global__ __launch_bounds__(256) void k_scan_block(const int* __restrict__ degi,
                                                    int* off, int* bsum) {
    __shared__ int sh[256];
    int t = threadIdx.x;
    int base = blockIdx.x * 1024;
    int v[4]; int s = 0;
#pragma unroll
    for (int j = 0; j < 4; j++) {
        int idx = base + t*4 + j;
        v[j] = (idx < NN) ? degi[idx] : 0;
        s += v[j];
    }
    sh[t] = s; __syncthreads();
    for (int ofs = 1; ofs < 256; ofs <<= 1) {
        int x = (t >= ofs) ? sh[t - ofs] : 0;
        __syncthreads();
        sh[t] += x;
        __syncthreads();
    }
    int ex = sh[t] - s;
#pragma unroll
    for (int j = 0; j < 4; j++) {
        int idx = base + t*4 + j;
        if (idx < NN) off[idx] = ex;
        ex += v[j];
    }
    if (t == 255) bsum[blockIdx.x] = sh[255];
}

__global__ __launch_bounds__(256) void k_scan_top(const int* __restrict__ bsum,
                                                  int* bpre, int nb) {
    __shared__ int sh[256];
    int t = threadIdx.x;
    int s = (t < nb) ? bsum[t] : 0;
    sh[t] = s; __syncthreads();
    for (int ofs = 1; ofs < 256; ofs <<= 1) {
        int x = (t >= ofs) ? sh[t - ofs] : 0;
        __syncthreads();
        sh[t] += x;
        __syncthreads();
    }
    if (t < nb) bpre[t] = sh[t] - s;
}

__global__ __launch_bounds__(256) void k_scan_add(int* off, const int* __restrict__ bpre) {
    int i = blockIdx.x*256 + threadIdx.x;
    if (i < NN) off[i] += bpre[i >> 10];
    if (i == 0) off[NN] = NE;
}

// ep = (src, 0, v0, v1) with v = pseudo*4 in [0,4); hat weights derive from v.
__global__ __launch_bounds__(256) void k_scatter(const int* __restrict__ src,
                                                 const int* __restrict__ dst,
                                                 const float* __restrict__ ea,
                                                 const int* __restrict__ off, int* cur,
                                                 int4* __restrict__ ep) {
    int e = blockIdx.x*256 + threadIdx.x;
    if (e >= NE) return;
    int d = dst[e];
    int p = off[d] + atomicAdd(&cur[d], 1);
    float v0 = ea[2*e]     * 4.f;
    float v1 = ea[2*e + 1] * 4.f;
    ep[p] = make_int4(src[e], 0, __float_as_int(v0), __float_as_int(v1));
}

// x (f32, [NN][32]) -> packed bf16 dwords
__global__ __launch_bounds__(256) void k_xbf(const float* __restrict__ x,
                                             unsigned short* __restrict__ xb) {
    int i = blockIdx.x*256 + threadIdx.x;
    if (i >= NN*8) return;
    float4 v = ((const float4*)x)[i];
    uint2 pk;
    pk.x = (unsigned)f2bf(v.x) | ((unsigned)f2bf(v.y) << 16);
    pk.y = (unsigned)f2bf(v.z) | ((unsigned)f2bf(v.w) << 16);
    ((uint2*)xb)[i] = pk;
}

// Pre-tile [W ; root] (f32, row-major [K,64]) into MFMA-B bf16 layout:
// Wb[((kk*4+cot)*64+lane)*8 + j] = src[k = kk*32+(lane>>4)*8+j][co = 16*cot+(lane&15)]
__global__ __launch_bounds__(256) void k_wprep(const float* __restrict__ W,
                                               const float* __restrict__ root,
                                               int KTC, unsigned short* Wb) {
    int tid = blockIdx.x*256 + threadIdx.x;
    int lane = tid & 63, cot = (tid >> 6) & 3, kk = tid >> 8;
    int co = 16*cot + (lane & 15);
    int kbase = kk*32 + ((lane >> 4) * 8);
    union { unsigned short s[8]; uint4 v; } u;
#pragma unroll
    for (int j = 0; j < 8; j++) {
        int k = kbase + j;
        float val = (k < KTC) ? W[(size_t)k*64 + co] : root[(size_t)(k - KTC)*64 + co];
        u.s[j] = f2bf(val);
    }
    *(uint4*)(Wb + (size_t)tid * 8) = u.v;
}

// ---------------- conv1 + convS fused: 16 nodes/block ----------------
// 512 threads, 8 waves. Half-wave (t>>5) owns node g.
// Within half-wave: chp = q&15 (bf16 channel pair), eh = q>>4 (edge slot).
// 8 edges per iteration per node (4 independent chains/lane).
__global__ __launch_bounds__(512, 4) void k_conv1s(
        const unsigned* __restrict__ Xbf,        // [NN][16] dwords (32 bf16 ch)
        const int* __restrict__ off,
        const int4* __restrict__ ep,
        const unsigned short* __restrict__ Wb1,
        const unsigned short* __restrict__ WbS,
        const float* __restrict__ b1,
        const float* __restrict__ bs,
        float* __restrict__ agg1,
        float* __restrict__ aggS) {
    __shared__ __align__(16) unsigned short hb[28*544];  // 30.5 KB
    const int t = threadIdx.x;
    const int g = t >> 5;          // node slot 0..15
    const int q = t & 31;
    const int chp = q & 15;        // channel pair -> channels 2chp, 2chp+1
    const int eh = q >> 4;         // edge slot
    const int n0 = blockIdx.x * 16;
    const int n = n0 + g;

    f32x2 h[25], hs = {0.f, 0.f};
#pragma unroll
    for (int i = 0; i < 25; ++i) h[i] = f32x2{0.f, 0.f};

    const int ebeg = off[n], eend = off[n + 1];
    const int last = eend - 1;
    const float rdeg = 1.f / (float)max(eend - ebeg, 1);

    for (int i = ebeg; i < eend; i += 8) {
        int4 p[4]; unsigned u[4];
#pragma unroll
        for (int uu = 0; uu < 4; ++uu)
            p[uu] = ld_ep(ep, (unsigned)min(i + 2*uu + eh, last));
#pragma unroll
        for (int uu = 0; uu < 4; ++uu) {
            u[uu] = ld_xu(Xbf, (unsigned)p[uu].x * 64u + (unsigned)chp * 4u);
            if (i + 2*uu + eh > last) u[uu] = 0u;
        }
#pragma unroll
        for (int uu = 0; uu < 4; ++uu)
            edge_acc2<true>(h, hs, p[uu], unpack2(u[uu]));
    }

    // ---- eh-reduce (shfl_xor over the 16-lane edge-slot stride) and dump ----
    // Lane (chp,eh) owns channel c = 2*chp + eh.
    const int c = 2*chp + eh;
    const int bw = us_idx(0, c, g);
#pragma unroll
    for (int wi = 0; wi < 25; ++wi)
        hb[wi*544 + bw] = f2bf(eh_reduce(h[wi], eh, 16) * rdeg);
    hb[26*544 + bw] = f2bf(eh_reduce(hs, eh, 16) * rdeg);
    {
        unsigned ux = Xbf[(unsigned)n * 16u + (unsigned)chp];
        unsigned short xb = eh ? (unsigned short)(ux >> 16)
                               : (unsigned short)(ux & 0xFFFFu);
        hb[25*544 + bw] = xb;   // x for root (r1)
        hb[27*544 + bw] = xb;   // x for root (rs)
    }
    __syncthreads();

    // ---- phase B (unchanged) ----
    const int lane = t & 63, w = t >> 6;
    const int m = lane & 15, qq = lane >> 4;
    const int co = (w & 3)*16 + m;
    if (w < 4) {
        f32x4 acc = {0.f, 0.f, 0.f, 0.f};
        for (int kk = 0; kk < 26; ++kk) {
            bf16x8 av = *(const bf16x8*)&hb[kk*544 + qq*136 + m*8];
            bf16x8 bv = *(const bf16x8*)(Wb1 + (size_t)((kk*4 + w)*64 + lane) * 8);
            acc = __builtin_amdgcn_mfma_f32_16x16x32_bf16(av, bv, acc, 0, 0, 0);
        }
        const float bb = b1[co];
#pragma unroll
        for (int r = 0; r < 4; ++r)
            agg1[(size_t)(n0 + qq*4 + r)*64 + co] = acc[r] + bb;
    } else {
        f32x4 accs = {0.f, 0.f, 0.f, 0.f};
#pragma unroll
        for (int s = 0; s < 2; ++s) {
            bf16x8 av = *(const bf16x8*)&hb[(26 + s)*544 + qq*136 + m*8];
            bf16x8 bv = *(const bf16x8*)(WbS + (size_t)((s*4 + (w & 3))*64 + lane) * 8);
            accs = __builtin_amdgcn_mfma_f32_16x16x32_bf16(av, bv, accs, 0, 0, 0);
        }
        const float bb = bs[co];
#pragma unroll
        for (int r = 0; r < 4; ++r)
            aggS[(size_t)(n0 + qq*4 + r)*64 + co] = accs[r] + bb;
    }
}

// ---------------- conv2: 16 nodes/block ----------------
// 512 threads, 8 waves. Wave w owns nodes 2w, 2w+1 sequentially.
// Lanes: chp = lane&31 (bf16 channel pair of 64 ch), eh = lane>>5 (edge slot):
// 8 edges per iteration per node (4 independent chains/lane).
__global__ __launch_bounds__(512, 4) void k_conv2(
        const unsigned* __restrict__ Xbf,        // h1 bf16: [NN][32] dwords (64 ch)
        const int* __restrict__ off,
        const int4* __restrict__ ep,
        const unsigned short* __restrict__ Wb2,
        const float* __restrict__ b2,
        float* __restrict__ agg) {
    __shared__ __align__(16) unsigned short hb[52*544];  // 56.6 KB
    const int t = threadIdx.x, lane = t & 63, w = t >> 6;
    const int n0 = blockIdx.x * 16;
    const int chp = lane & 31, eh = lane >> 5;
    const int c = 2*chp + eh;          // channel owned after eh-reduce
    const int kh = c >> 5, r = c & 31; // k = wi*64 + c -> kstep wi*2+kh

#pragma unroll
    for (int nn = 0; nn < 2; ++nn) {
        const int g = 2*w + nn;
        const int n = n0 + g;
        f32x2 h[25]; f32x2 hsd = {0.f, 0.f};
#pragma unroll
        for (int i = 0; i < 25; ++i) h[i] = f32x2{0.f, 0.f};

        const int ebeg = off[n], eend = off[n + 1];
        const int last = eend - 1;
        const float rdeg = 1.f / (float)max(eend - ebeg, 1);

        for (int i = ebeg; i < eend; i += 8) {
            int4 p[4]; unsigned u[4];
#pragma unroll
            for (int uu = 0; uu < 4; ++uu)
                p[uu] = ld_ep(ep, (unsigned)min(i + 2*uu + eh, last));
#pragma unroll
            for (int uu = 0; uu < 4; ++uu) {
                u[uu] = ld_xu(Xbf, (unsigned)p[uu].x * 128u + (unsigned)chp * 4u);
                if (i + 2*uu + eh > last) u[uu] = 0u;
            }
#pragma unroll
            for (int uu = 0; uu < 4; ++uu)
                edge_acc2<false>(h, hsd, p[uu], unpack2(u[uu]));
        }

        // eh-reduce via shfl_xor(32); dump bf16 fragments
        const int bw = us_idx(0, r, g);
#pragma unroll
        for (int wi = 0; wi < 25; ++wi)
            hb[(wi*2 + kh)*544 + bw] = f2bf(eh_reduce(h[wi], eh, 32) * rdeg);
        {
            unsigned ux = Xbf[(unsigned)n * 32u + (unsigned)chp];
            hb[(50 + kh)*544 + bw] =
                (unsigned short)(eh ? (ux >> 16) : (ux & 0xFFFFu));
        }
    }
    __syncthreads();

    if (w >= 4) return;

    const int m = lane & 15, qq = lane >> 4;
    f32x4 acc = {0.f, 0.f, 0.f, 0.f};
    for (int kk = 0; kk < 52; ++kk) {
        bf16x8 av = *(const bf16x8*)&hb[kk*544 + qq*136 + m*8];
        bf16x8 bv = *(const bf16x8*)(Wb2 + (size_t)((kk*4 + w)*64 + lane) * 8);
        acc = __builtin_amdgcn_mfma_f32_16x16x32_bf16(av, bv, acc, 0, 0, 0);
    }
    const int co = w*16 + m;
    const float bb = b2[co];
#pragma unroll
    for (int rr = 0; rr < 4; ++rr)
        agg[(size_t)(n0 + qq*4 + rr)*64 + co] = acc[rr] + bb;
}

// ---------------- batch norm ----------------
__global__ __launch_bounds__(256) void k_bnstats(const float* __restrict__ agg, float* stats) {
    __shared__ float sh0[256], sh1[256];
    int t = threadIdx.x;
    float s = 0.f, ss = 0.f;
    int stride = gridDim.x * 256;
    for (int i = blockIdx.x*256 + t; i < NN*64; i += stride) {
        float v = agg[i];
        s += v; ss += v*v;
    }
    sh0[t] = s; sh1[t] = ss;
    __syncthreads();
    if (t < 64) {
        float a = sh0[t] + sh0[t+64] + sh0[t+128] + sh0[t+192];
        float b = sh1[t] + sh1[t+64] + sh1[t+128] + sh1[t+192];
        atomicAdd(&stats[t], a);
        atomicAdd(&stats[64 + t], b);
    }
}

__device__ __forceinline__ float eluf(float u) { return u > 0.f ? u : expm1f(u); }

// BN + ELU, emitting packed bf16 h1 (feeds conv2's gathers directly)
__global__ __launch_bounds__(256) void k_bn_elu(const float* __restrict__ agg,
                                                const float* __restrict__ stats,
                                                const float* __restrict__ gamma,
                                                const float* __restrict__ beta,
                                                unsigned short* __restrict__ outb) {
    int i = blockIdx.x*256 + threadIdx.x;
    if (i >= NN*16) return;
    float4 v = ((const float4*)agg)[i];
    float r[4] = {v.x, v.y, v.z, v.w};
    int c0 = (i << 2) & 63;
#pragma unroll
    for (int j = 0; j < 4; j++) {
        int c = c0 + j;
        float mu = stats[c] * (1.f/NN);
        float var = stats[64 + c] * (1.f/NN) - mu*mu;
        float sc = gamma[c] * rsqrtf(fmaxf(var, 0.f) + 1e-5f);
        r[j] = eluf((r[j] - mu)*sc + beta[c]);
    }
    uint2 pk;
    pk.x = (unsigned)f2bf(r[0]) | ((unsigned)f2bf(r[1]) << 16);
    pk.y = (unsigned)f2bf(r[2]) | ((unsigned)f2bf(r[3]) << 16);
    ((uint2*)outb)[i] = pk;
}

__global__ __launch_bounds__(256) void k_bn_final(const float* __restrict__ a2,
                                                  const float* __restrict__ st2,
                                                  const float* __restrict__ g2,
                                                  const float* __restrict__ be2,
                                                  const float* __restrict__ as,
                                                  const float* __restrict__ sts,
                                                  const float* __restrict__ gs,
                                                  const float* __restrict__ bes,
                                                  float* __restrict__ out) {
    int i = blockIdx.x*256 + threadIdx.x;
    if (i >= NN*16) return;
    float4 v2 = ((const float4*)a2)[i];
    float4 vs = ((const float4*)as)[i];
    float r2v[4] = {v2.x, v2.y, v2.z, v2.w};
    float rsv[4] = {vs.x, vs.y, vs.z, vs.w};
    float o[4];
    int c0 = (i << 2) & 63;
#pragma unroll
    for (int j = 0; j < 4; j++) {
        int c = c0 + j;
        float mu2 = st2[c] * (1.f/NN);
        float var2 = st2[64 + c] * (1.f/NN) - mu2*mu2;
        float sc2 = g2[c] * rsqrtf(fmaxf(var2, 0.f) + 1e-5f);
        float mus = sts[c] * (1.f/NN);
        float vars = sts[64 + c] * (1.f/NN) - mus*mus;
        float scs = gs[c] * rsqrtf(fmaxf(vars, 0.f) + 1e-5f);
        float u = (r2v[j] - mu2)*sc2 + be2[c] + (rsv[j] - mus)*scs + bes[c];
        o[j] = eluf(u);
    }
    ((float4*)out)[i] = make_float4(o[0], o[1], o[2], o[3]);
}

extern "C" void kernel_launch(void* const* d_in, const int* in_sizes, int n_in,
                              void* d_out, int out_size, void* d_ws, size_t ws_size,
                              hipStream_t stream) {
    const float* x   = (const float*)d_in[0];
    const int*   ei  = (const int*)d_in[1];
    const float* ea  = (const float*)d_in[2];
    const float* w1  = (const float*)d_in[3];
    const float* r1  = (const float*)d_in[4];
    const float* b1  = (const float*)d_in[5];
    const float* g1  = (const float*)d_in[6];
    const float* be1 = (const float*)d_in[7];
    const float* w2  = (const float*)d_in[8];
    const float* r2  = (const float*)d_in[9];
    const float* b2  = (const float*)d_in[10];
    const float* g2  = (const float*)d_in[11];
    const float* be2 = (const float*)d_in[12];
    const float* wsN = (const float*)d_in[13];
    const float* rs  = (const float*)d_in[14];
    const float* bs  = (const float*)d_in[15];
    const float* gs  = (const float*)d_in[16];
    const float* bes = (const float*)d_in[17];
    const int* srcp = ei;
    const int* dstp = ei + NE;

    char* wsb = (char*)d_ws;
    size_t o = 0;
    auto alloc = [&](size_t bytes) -> char* {
        char* p = wsb + o;
        o += (bytes + 255) & ~(size_t)255;
        return p;
    };
    int*    degi    = (int*)   alloc((size_t)NN * 4);
    int*    cur     = (int*)   alloc((size_t)NN * 4);
    int*    off     = (int*)   alloc((size_t)(NN + 1) * 4);
    int*    bsum    = (int*)   alloc(256 * 4);
    int*    bpre    = (int*)   alloc(256 * 4);
    int4*   ep      = (int4*)  alloc((size_t)NE * 16);
    unsigned short* Wb1 = (unsigned short*)alloc(26 * 4096);
    unsigned short* WbS = (unsigned short*)alloc(2 * 4096);
    unsigned short* Wb2 = (unsigned short*)alloc(52 * 4096);
    float*  agg1    = (float*) alloc((size_t)NN * 64 * 4);  // reused for conv2 output
    float*  aggS    = (float*) alloc((size_t)NN * 64 * 4);
    unsigned short* h1bf = (unsigned short*)alloc((size_t)NN * 64 * 2);
    unsigned short* xbf  = (unsigned short*)alloc((size_t)NN * 32 * 2);
    float*  stats   = (float*) alloc(384 * 4);
    (void)ws_size; (void)in_sizes; (void)n_in; (void)out_size;

    float* out = (float*)d_out;

    k_zero<<<196, 256, 0, stream>>>(degi, cur, stats);
    k_hist<<<3125, 256, 0, stream>>>(dstp, degi);
    k_scan_block<<<49, 256, 0, stream>>>(degi, off, bsum);
    k_scan_top<<<1, 256, 0, stream>>>(bsum, bpre, 49);
    k_scan_add<<<196, 256, 0, stream>>>(off, bpre);
    k_scatter<<<3125, 256, 0, stream>>>(srcp, dstp, ea, off, cur, ep);

    k_xbf<<<1563, 256, 0, stream>>>(x, xbf);
    k_wprep<<<26, 256, 0, stream>>>(w1, r1, 800, Wb1);
    k_wprep<<<2, 256, 0, stream>>>(wsN, rs, 32, WbS);
    k_wprep<<<52, 256, 0, stream>>>(w2, r2, 1600, Wb2);

    k_conv1s<<<3125, 512, 0, stream>>>((const unsigned*)xbf, off, ep, Wb1, WbS,
                                       b1, bs, agg1, aggS);
    k_bnstats<<<256, 256, 0, stream>>>(agg1, stats);
    k_bn_elu<<<3125, 256, 0, stream>>>(agg1, stats, g1, be1, h1bf);

    k_conv2<<<3125, 512, 0, stream>>>((const unsigned*)h1bf, off, ep, Wb2, b2, agg1);
    k_bnstats<<<256, 256, 0, stream>>>(agg1, stats + 128);
    k_bnstats<<<256, 256, 0, stream>>>(aggS, stats + 256);
    k_bn_final<<<3125, 256, 0, stream>>>(agg1, stats + 128, g2, be2,
                                         aggS, stats + 256, gs, bes, out);
}